// Round 1
// baseline (279.260 us; speedup 1.0000x reference)
//
#include <hip/hip_runtime.h>
#include <math.h>

#define HW 2304           // 48*48
#define O192 192
#define SCALE_F 0.35355339059327373f   // 8^-0.5

// ---------------- Kernel A: 1x1 conv -> q,k,v ----------------
// QKV layout: [b][p][o] (o fastest, 192), p = y*48+x.
// V2 layout:  [b][h][j][c8] (8 floats contiguous per j) for uniform 32B reads.
__global__ __launch_bounds__(256) void qkv_kernel(
    const float* __restrict__ F, const float* __restrict__ W,
    float* __restrict__ QKV, float* __restrict__ V2) {
  int idx = blockIdx.x * 256 + threadIdx.x;   // 294912 = 2*2304*64
  int p  = idx % HW;
  int r  = idx / HW;       // 0..127
  int o0 = r & 63;
  int b  = r >> 6;
  const float* f  = F + (b * 64) * HW + p;
  const float* w0 = W + o0 * 64;            // q row
  const float* w1 = W + (o0 + 64) * 64;     // k row
  const float* w2 = W + (o0 + 128) * 64;    // v row
  float aq = 0.f, ak = 0.f, av = 0.f;
  #pragma unroll 8
  for (int c = 0; c < 64; c++) {
    float fv = f[c * HW];                   // coalesced (p fast across lanes)
    aq = fmaf(w0[c], fv, aq);               // o0 wave-uniform -> scalar loads
    ak = fmaf(w1[c], fv, ak);
    av = fmaf(w2[c], fv, av);
  }
  float* qp = QKV + (b * HW + p) * O192;
  qp[o0]       = aq;
  qp[o0 + 64]  = ak;
  qp[o0 + 128] = av;
  V2[(((b << 3) + (o0 >> 3)) * HW + p) * 8 + (o0 & 7)] = av;
}

// ---------------- Kernel B: 11x11 stride-8 conv + bias + exact GELU ----------
// grid 256 = (T in {q,k}) * b * o.  Block 256 = 4 waves; wave handles 9 positions,
// lane = input channel c.  QD layout: [T][b][o][pos36].
__global__ __launch_bounds__(256) void conv_kernel(
    const float* __restrict__ QKV, const float* __restrict__ Wq,
    const float* __restrict__ Bq, const float* __restrict__ Wk,
    const float* __restrict__ Bk, float* __restrict__ QD) {
  __shared__ float sW[7744];   // 64 c * 121 taps for this output channel o
  int blk = blockIdx.x;
  int T = blk >> 7;
  int b = (blk >> 6) & 1;
  int o = blk & 63;
  const float* Wg = T ? Wk : Wq;
  float bias = T ? Bk[o] : Bq[o];
  for (int i = threadIdx.x; i < 7744; i += 256) sW[i] = Wg[o * 7744 + i];
  __syncthreads();
  int wv = threadIdx.x >> 6;
  int c  = threadIdx.x & 63;
  for (int pp = 0; pp < 9; pp++) {
    int pos = wv * 9 + pp;
    int oy = pos / 6, ox = pos % 6;
    float acc = 0.f;
    for (int ky = 0; ky < 11; ky++) {
      int y = oy * 8 - 2 + ky;
      if ((unsigned)y < 48u) {
        #pragma unroll
        for (int kx = 0; kx < 11; kx++) {
          int x = ox * 8 - 2 + kx;
          if ((unsigned)x < 48u) {
            // lanes read 64 consecutive floats: coalesced
            acc = fmaf(QKV[(b * HW + y * 48 + x) * O192 + T * 64 + c],
                       sW[c * 121 + ky * 11 + kx], acc);
          }
        }
      }
    }
    #pragma unroll
    for (int off = 32; off; off >>= 1) acc += __shfl_down(acc, off, 64);
    if (c == 0) {
      float g = acc + bias;
      float ge = 0.5f * g * (1.0f + erff(g * 0.70710678118654752f));
      QD[((T * 2 + b) * 64 + o) * 36 + pos] = ge;
    }
  }
}

// ---------------- Kernel C: dots (36x36 per b,h) -> E = exp(scale * qd.kd) ----
__global__ __launch_bounds__(256) void dots_kernel(
    const float* __restrict__ QD, float* __restrict__ E) {
  int idx = blockIdx.x * 256 + threadIdx.x;   // 20736 = 16*36*36
  if (idx >= 16 * 36 * 36) return;
  int J  = idx % 36;
  int I  = (idx / 36) % 36;
  int bh = idx / 1296;
  int b = bh >> 3, h = bh & 7;
  float acc = 0.f;
  #pragma unroll
  for (int c8 = 0; c8 < 8; c8++) {
    float qv = QD[((0 + b) * 64 + h * 8 + c8) * 36 + I];        // T=0
    float kv = QD[((2 + b) * 64 + h * 8 + c8) * 36 + J];        // T=1
    acc = fmaf(qv, kv, acc);
  }
  E[idx] = __expf(SCALE_F * acc);
}

// ---------------- Kernel D: fused factored attention ------------------------
// One block per (b,h,I).  lane = row r (i = I*64+r); 8 waves split jy rows.
// w(i,j) = E[I,J] * expA_i[jy] * expB_i[jx];  out = (sum w*v) / (sum w).
__global__ __launch_bounds__(512) void attn_kernel(
    const float* __restrict__ QKV, const float* __restrict__ V2,
    const float* __restrict__ E, const float* __restrict__ PH,
    const float* __restrict__ PW, float* __restrict__ out) {
  __shared__ float sE[36];
  __shared__ float sAB[64 * 97];      // per-row expA[48] then expB[48], stride 97
  __shared__ float sRed[8 * 64 * 9];  // per-wave partials (8 acc + Z)
  __shared__ float sZinv[64];
  int bh = blockIdx.x / 36;
  int I  = blockIdx.x % 36;
  int b = bh >> 3, h = bh & 7;
  int tid = threadIdx.x;
  if (tid < 36) sE[tid] = E[bh * 1296 + I * 36 + tid];
  // ---- prologue: expA/expB for the 64 rows of this I-block ----
  {
    int r = tid >> 3, s = tid & 7;
    const float* qr = QKV + (b * HW + I * 64 + r) * O192 + h * 8;
    float4 qa = *(const float4*)qr;
    float4 qb = *(const float4*)(qr + 4);
    #pragma unroll
    for (int m = 0; m < 12; m++) {
      int idx = s * 12 + m;                // 0..95
      const float* P = (idx < 48) ? (PH + idx) : (PW + (idx - 48));
      float v = qa.x * P[0]   + qa.y * P[48]  + qa.z * P[96]  + qa.w * P[144]
              + qb.x * P[192] + qb.y * P[240] + qb.z * P[288] + qb.w * P[336];
      sAB[r * 97 + idx] = __expf(v);
    }
  }
  __syncthreads();
  int wv = tid >> 6, lane = tid & 63;
  float eB[48];                         // register-resident, compile-time indexed
  #pragma unroll
  for (int x = 0; x < 48; x++) eB[x] = sAB[lane * 97 + 48 + x];
  float acc[9];
  #pragma unroll
  for (int c = 0; c < 9; c++) acc[c] = 0.f;
  const float* vbase = V2 + ((b * 8 + h) * HW) * 8;
  for (int t = 0; t < 6; t++) {         // 6 jy rows per wave
    int jy = wv * 6 + t;
    float eA = sAB[lane * 97 + jy];
    int j0 = jy * 48;
    #pragma unroll
    for (int c3 = 0; c3 < 6; c3++) {    // 6 chunks of 8 j; J constant per chunk
      int jf = j0 + c3 * 8;
      float tA = eA * sE[jf >> 6];
      const float* vp = vbase + jf * 8;
      #pragma unroll
      for (int u = 0; u < 8; u++) {
        float wgt = tA * eB[c3 * 8 + u];
        float4 lo = *(const float4*)(vp + u * 8);      // wave-uniform address
        float4 hi = *(const float4*)(vp + u * 8 + 4);
        acc[0] = fmaf(wgt, lo.x, acc[0]);
        acc[1] = fmaf(wgt, lo.y, acc[1]);
        acc[2] = fmaf(wgt, lo.z, acc[2]);
        acc[3] = fmaf(wgt, lo.w, acc[3]);
        acc[4] = fmaf(wgt, hi.x, acc[4]);
        acc[5] = fmaf(wgt, hi.y, acc[5]);
        acc[6] = fmaf(wgt, hi.z, acc[6]);
        acc[7] = fmaf(wgt, hi.w, acc[7]);
        acc[8] += wgt;
      }
    }
  }
  {
    float* rp = sRed + (wv * 64 + lane) * 9;
    #pragma unroll
    for (int c = 0; c < 9; c++) rp[c] = acc[c];
  }
  __syncthreads();
  if (tid < 64) {
    float z = 0.f;
    #pragma unroll
    for (int w = 0; w < 8; w++) z += sRed[(w * 64 + tid) * 9 + 8];
    sZinv[tid] = 1.0f / z;
  }
  __syncthreads();
  {
    int c = tid >> 6, r = tid & 63;     // c 0..7
    float v = 0.f;
    #pragma unroll
    for (int w = 0; w < 8; w++) v += sRed[(w * 64 + r) * 9 + c];
    out[(b * 64 + h * 8 + c) * HW + I * 64 + r] = v * sZinv[r];   // coalesced
  }
}

extern "C" void kernel_launch(void* const* d_in, const int* in_sizes, int n_in,
                              void* d_out, int out_size, void* d_ws, size_t ws_size,
                              hipStream_t stream) {
  const float* F    = (const float*)d_in[0];   // [2,64,48,48]
  const float* Wqkv = (const float*)d_in[1];   // [192,64,1,1]
  const float* Wq   = (const float*)d_in[2];   // [64,64,11,11]
  const float* Bq   = (const float*)d_in[3];   // [64]
  const float* Wk   = (const float*)d_in[4];   // [64,64,11,11]
  const float* Bk   = (const float*)d_in[5];   // [64]
  const float* PH   = (const float*)d_in[6];   // [8,48]
  const float* PW   = (const float*)d_in[7];   // [8,48]
  float* out = (float*)d_out;                  // [2,64,48,48] f32

  float* ws  = (float*)d_ws;
  float* QKV = ws;                      // 2*2304*192   = 884736 floats
  float* V2  = QKV + 2 * HW * O192;     // 2*8*2304*8   = 294912 floats
  float* QD  = V2 + 2 * 8 * HW * 8;     // 2*2*64*36    = 9216 floats
  float* E   = QD + 2 * 2 * 64 * 36;    // 16*36*36     = 20736 floats

  qkv_kernel <<<1152, 256, 0, stream>>>(F, Wqkv, QKV, V2);
  conv_kernel<<<256,  256, 0, stream>>>(QKV, Wq, Bq, Wk, Bk, QD);
  dots_kernel<<<81,   256, 0, stream>>>(QD, E);
  attn_kernel<<<576,  512, 0, stream>>>(QKV, V2, E, PH, PW, out);
}

// Round 2
// 214.302 us; speedup vs baseline: 1.3031x; 1.3031x over previous
//
#include <hip/hip_runtime.h>
#include <math.h>

#define HW 2304           // 48*48
#define O192 192
#define SCALE_F 0.35355339059327373f   // 8^-0.5

// ---------------- Kernel A: 1x1 conv -> q,k (QKV) and v (V2) ----------------
// QKV layout: [b][p][o] (o fastest, 192), p = y*48+x.  (v slots unused/unwritten)
// V2 layout:  [b][h][j][c8] (8 floats contiguous per j).
// Weight rows staged in LDS to avoid s_load/lgkmcnt(0) drains in the loop.
__global__ __launch_bounds__(256) void qkv_kernel(
    const float* __restrict__ F, const float* __restrict__ W,
    float* __restrict__ QKV, float* __restrict__ V2) {
  __shared__ float sW[384];   // two (o0) sets x 3 rows x 64
  int blk = blockIdx.x;
  int idx0 = blk * 256;
  int r0 = idx0 / HW;                 // first r in this block
  int r1 = (idx0 + 255) / HW;         // last r (r0 or r0+1)
  int tid = threadIdx.x;
  if (tid < 192) {
    int g = tid >> 6, c = tid & 63;
    int o0a = r0 & 63;
    sW[tid] = W[(o0a + g * 64) * 64 + c];
  } else {
    int t2 = tid - 192;               // 0..63
    // stage set B rows with 192 threads? only 64 here; loop below covers rest
  }
  // set B (for r1) staged by threads 0..191 on a second pass if r1 != r0
  __syncthreads();
  if (tid < 192) {
    int g = tid >> 6, c = tid & 63;
    int o0b = r1 & 63;
    sW[192 + tid] = W[(o0b + g * 64) * 64 + c];
  }
  __syncthreads();
  int idx = idx0 + tid;               // 294912 = 2*2304*64
  int p  = idx % HW;
  int r  = idx / HW;                  // 0..127
  int o0 = r & 63;
  int b  = r >> 6;
  int sel = (r == r0) ? 0 : 192;
  const float* f = F + (b * 64) * HW + p;
  float aq = 0.f, ak = 0.f, av = 0.f;
  #pragma unroll 8
  for (int c = 0; c < 64; c++) {
    float fv = f[c * HW];             // coalesced (p fast across lanes)
    aq = fmaf(sW[sel + c],       fv, aq);   // LDS broadcast reads
    ak = fmaf(sW[sel + 64 + c],  fv, ak);
    av = fmaf(sW[sel + 128 + c], fv, av);
  }
  float* qp = QKV + (b * HW + p) * O192;
  qp[o0]      = aq;
  qp[o0 + 64] = ak;
  V2[(((b << 3) + (o0 >> 3)) * HW + p) * 8 + (o0 & 7)] = av;
}

// ---------------- Kernel B: 11x11 stride-8 conv + bias + exact GELU ----------
// grid 768 = 3 pos-groups * (T in {q,k}) * b * o.  Block 256 = 4 waves; each
// wave handles 3 positions; lane = input channel c.  QD layout: [T][b][o][pos36].
__global__ __launch_bounds__(256) void conv_kernel(
    const float* __restrict__ QKV, const float* __restrict__ Wq,
    const float* __restrict__ Bq, const float* __restrict__ Wk,
    const float* __restrict__ Bk, float* __restrict__ QD) {
  __shared__ float sW[7744];   // 64 c * 121 taps for this output channel o
  int blk = blockIdx.x;
  int sub = blk % 3;
  int oo  = blk / 3;          // 0..255
  int T = oo >> 7;
  int b = (oo >> 6) & 1;
  int o = oo & 63;
  const float* Wg = T ? Wk : Wq;
  float bias = T ? Bk[o] : Bq[o];
  for (int i = threadIdx.x; i < 7744; i += 256) sW[i] = Wg[o * 7744 + i];
  __syncthreads();
  int wv = threadIdx.x >> 6;
  int c  = threadIdx.x & 63;
  for (int pp = 0; pp < 3; pp++) {
    int pos = sub * 12 + wv * 3 + pp;        // 0..35
    int oy = pos / 6, ox = pos % 6;
    float acc = 0.f;
    for (int ky = 0; ky < 11; ky++) {
      int y = oy * 8 - 2 + ky;
      if ((unsigned)y < 48u) {
        #pragma unroll
        for (int kx = 0; kx < 11; kx++) {
          int x = ox * 8 - 2 + kx;
          if ((unsigned)x < 48u) {
            acc = fmaf(QKV[(b * HW + y * 48 + x) * O192 + T * 64 + c],
                       sW[c * 121 + ky * 11 + kx], acc);
          }
        }
      }
    }
    #pragma unroll
    for (int off = 32; off; off >>= 1) acc += __shfl_down(acc, off, 64);
    if (c == 0) {
      float g = acc + bias;
      float ge = 0.5f * g * (1.0f + erff(g * 0.70710678118654752f));
      QD[((T * 2 + b) * 64 + o) * 36 + pos] = ge;
    }
  }
}

// ---------------- Kernel C: dots (36x36 per b,h) -> E = exp(scale * qd.kd) ----
__global__ __launch_bounds__(256) void dots_kernel(
    const float* __restrict__ QD, float* __restrict__ E) {
  int idx = blockIdx.x * 256 + threadIdx.x;   // 20736 = 16*36*36
  if (idx >= 16 * 36 * 36) return;
  int J  = idx % 36;
  int I  = (idx / 36) % 36;
  int bh = idx / 1296;
  int b = bh >> 3, h = bh & 7;
  float acc = 0.f;
  #pragma unroll
  for (int c8 = 0; c8 < 8; c8++) {
    float qv = QD[((0 + b) * 64 + h * 8 + c8) * 36 + I];        // T=0
    float kv = QD[((2 + b) * 64 + h * 8 + c8) * 36 + J];        // T=1
    acc = fmaf(qv, kv, acc);
  }
  E[idx] = __expf(SCALE_F * acc);
}

// ---------------- Kernel D: fused factored attention ------------------------
// One block per (b,h,I).  lane = row r (i = I*64+r); 8 waves split jy rows.
// V staged in LDS in two 1152-j phases so inner-loop V reads are ds_read
// broadcasts (fine-grained lgkmcnt pipelining) instead of s_load drains.
// w(i,j) = E[I,J] * expA_i[jy] * expB_i[jx];  out = (sum w*v) / (sum w).
__global__ __launch_bounds__(512, 4) void attn_kernel(
    const float* __restrict__ QKV, const float* __restrict__ V2,
    const float* __restrict__ E, const float* __restrict__ PH,
    const float* __restrict__ PW, float* __restrict__ out) {
  __shared__ __align__(16) float sV[1152 * 8];   // 36864 B, one phase of V
  __shared__ __align__(16) float sPHT[48 * 8];   // PH transposed [y][c]
  __shared__ __align__(16) float sPWT[48 * 8];   // PW transposed [x][c]
  __shared__ float sE[36];
  __shared__ float sRed[8 * 64 * 9];             // 18432 B per-wave partials
  __shared__ float sZinv[64];
  int bh = blockIdx.x / 36;
  int I  = blockIdx.x % 36;
  int b = bh >> 3, h = bh & 7;
  int tid = threadIdx.x;
  // ---- stage small tables ----
  if (tid < 384) sPHT[tid] = PH[(tid & 7) * 48 + (tid >> 3)];
  else { int i = tid - 384; sPWT[i] = PW[(i & 7) * 48 + (i >> 3)]; }   // 0..127
  if (tid < 256) { int i = tid + 128; sPWT[i] = PW[(i & 7) * 48 + (i >> 3)]; }
  if (tid < 36) sE[tid] = E[bh * 1296 + I * 36 + tid];
  int wv = tid >> 6, lane = tid & 63;
  // ---- per-lane q row (each wave holds the same 64 rows) ----
  const float* qr = QKV + (b * HW + I * 64 + lane) * O192 + h * 8;
  float4 qa = *(const float4*)qr;
  float4 qb = *(const float4*)(qr + 4);
  __syncthreads();
  // ---- per-lane eB[48] in registers ----
  float eB[48];
  #pragma unroll
  for (int x = 0; x < 48; x++) {
    float4 p0 = *(const float4*)(sPWT + x * 8);
    float4 p1 = *(const float4*)(sPWT + x * 8 + 4);
    float v = qa.x * p0.x + qa.y * p0.y + qa.z * p0.z + qa.w * p0.w
            + qb.x * p1.x + qb.y * p1.y + qb.z * p1.z + qb.w * p1.w;
    eB[x] = __expf(v);
  }
  float acc[9];
  #pragma unroll
  for (int c = 0; c < 9; c++) acc[c] = 0.f;
  const float4* vsrc = (const float4*)(V2 + (size_t)bh * (HW * 8));
  for (int p = 0; p < 2; p++) {
    // stage this phase's V half: j in [p*1152, p*1152+1152)
    __syncthreads();
    {
      float4* dst = (float4*)sV;
      #pragma unroll
      for (int k = 0; k < 5; k++) {
        int i = tid + k * 512;
        if (i < 2304) dst[i] = vsrc[p * 2304 + i];
      }
    }
    __syncthreads();
    #pragma unroll
    for (int t = 0; t < 3; t++) {
      int jy = p * 24 + wv * 3 + t;
      float4 h0 = *(const float4*)(sPHT + jy * 8);
      float4 h1 = *(const float4*)(sPHT + jy * 8 + 4);
      float eA = __expf(qa.x * h0.x + qa.y * h0.y + qa.z * h0.z + qa.w * h0.w
                      + qb.x * h1.x + qb.y * h1.y + qb.z * h1.z + qb.w * h1.w);
      #pragma unroll
      for (int c3 = 0; c3 < 6; c3++) {
        float tA = eA * sE[(jy * 6 + c3) >> 3];
        const float* vp = sV + (((jy - p * 24) * 48) + c3 * 8) * 8;
        #pragma unroll
        for (int u = 0; u < 8; u++) {
          float wgt = tA * eB[c3 * 8 + u];
          float4 lo = *(const float4*)(vp + u * 8);      // ds_read broadcast
          float4 hi = *(const float4*)(vp + u * 8 + 4);
          acc[0] = fmaf(wgt, lo.x, acc[0]);
          acc[1] = fmaf(wgt, lo.y, acc[1]);
          acc[2] = fmaf(wgt, lo.z, acc[2]);
          acc[3] = fmaf(wgt, lo.w, acc[3]);
          acc[4] = fmaf(wgt, hi.x, acc[4]);
          acc[5] = fmaf(wgt, hi.y, acc[5]);
          acc[6] = fmaf(wgt, hi.z, acc[6]);
          acc[7] = fmaf(wgt, hi.w, acc[7]);
          acc[8] += wgt;
        }
      }
    }
  }
  {
    float* rp = sRed + (wv * 64 + lane) * 9;
    #pragma unroll
    for (int c = 0; c < 9; c++) rp[c] = acc[c];
  }
  __syncthreads();
  if (tid < 64) {
    float z = 0.f;
    #pragma unroll
    for (int w = 0; w < 8; w++) z += sRed[(w * 64 + tid) * 9 + 8];
    sZinv[tid] = 1.0f / z;
  }
  __syncthreads();
  {
    int c = tid >> 6, r = tid & 63;     // c 0..7
    float v = 0.f;
    #pragma unroll
    for (int w = 0; w < 8; w++) v += sRed[(w * 64 + r) * 9 + c];
    out[(b * 64 + h * 8 + c) * HW + I * 64 + r] = v * sZinv[r];   // coalesced
  }
}

extern "C" void kernel_launch(void* const* d_in, const int* in_sizes, int n_in,
                              void* d_out, int out_size, void* d_ws, size_t ws_size,
                              hipStream_t stream) {
  const float* F    = (const float*)d_in[0];   // [2,64,48,48]
  const float* Wqkv = (const float*)d_in[1];   // [192,64,1,1]
  const float* Wq   = (const float*)d_in[2];   // [64,64,11,11]
  const float* Bq   = (const float*)d_in[3];   // [64]
  const float* Wk   = (const float*)d_in[4];   // [64,64,11,11]
  const float* Bk   = (const float*)d_in[5];   // [64]
  const float* PH   = (const float*)d_in[6];   // [8,48]
  const float* PW   = (const float*)d_in[7];   // [8,48]
  float* out = (float*)d_out;                  // [2,64,48,48] f32

  float* ws  = (float*)d_ws;
  float* QKV = ws;                      // 2*2304*192   = 884736 floats
  float* V2  = QKV + 2 * HW * O192;     // 2*8*2304*8   = 294912 floats
  float* QD  = V2 + 2 * 8 * HW * 8;     // 2*2*64*36    = 9216 floats
  float* E   = QD + 2 * 2 * 64 * 36;    // 16*36*36     = 20736 floats

  qkv_kernel <<<1152, 256, 0, stream>>>(F, Wqkv, QKV, V2);
  conv_kernel<<<768,  256, 0, stream>>>(QKV, Wq, Bq, Wk, Bk, QD);
  dots_kernel<<<81,   256, 0, stream>>>(QD, E);
  attn_kernel<<<576,  512, 0, stream>>>(QKV, V2, E, PH, PW, out);
}

// Round 3
// 143.372 us; speedup vs baseline: 1.9478x; 1.4947x over previous
//
#include <hip/hip_runtime.h>
#include <math.h>

#define HW 2304           // 48*48
#define O192 192
#define SCALE_F 0.35355339059327373f   // 8^-0.5

// ---------------- Kernel A: 1x1 conv -> q,k (QKV) and v (V2) ----------------
// QKV layout: [b][p][o] (o fastest, 192), p = y*48+x.  (v slots unused)
// V2 layout:  [b][h][j][c8] (8 floats contiguous per j).
__global__ __launch_bounds__(256) void qkv_kernel(
    const float* __restrict__ F, const float* __restrict__ W,
    float* __restrict__ QKV, float* __restrict__ V2) {
  __shared__ __align__(16) float sW[384];   // two o0 sets x {q,k,v} rows x 64
  int blk = blockIdx.x;
  int idx0 = blk * 256;
  int r0 = idx0 / HW;                 // first r in this block
  int r1 = (idx0 + 255) / HW;         // last r (r0 or r0+1)
  int tid = threadIdx.x;
  if (tid < 192) {
    int g = tid >> 6, c = tid & 63;
    sW[tid]       = W[((r0 & 63) + g * 64) * 64 + c];
    sW[192 + tid] = W[((r1 & 63) + g * 64) * 64 + c];
  }
  __syncthreads();
  int idx = idx0 + tid;               // 294912 = 2*2304*64
  int p  = idx % HW;
  int r  = idx / HW;                  // 0..127
  int o0 = r & 63;
  int b  = r >> 6;
  const float4* w4 = (const float4*)(sW + ((r == r0) ? 0 : 192));
  const float* f = F + (b * 64) * HW + p;
  float aq = 0.f, ak = 0.f, av = 0.f;
  #pragma unroll 4
  for (int c4 = 0; c4 < 16; c4++) {
    float4 wq = w4[c4];               // LDS broadcast, b128
    float4 wk = w4[16 + c4];
    float4 wv = w4[32 + c4];
    float f0 = f[(c4 * 4 + 0) * HW];  // coalesced (p fast across lanes)
    float f1 = f[(c4 * 4 + 1) * HW];
    float f2 = f[(c4 * 4 + 2) * HW];
    float f3 = f[(c4 * 4 + 3) * HW];
    aq = fmaf(wq.x, f0, aq); ak = fmaf(wk.x, f0, ak); av = fmaf(wv.x, f0, av);
    aq = fmaf(wq.y, f1, aq); ak = fmaf(wk.y, f1, ak); av = fmaf(wv.y, f1, av);
    aq = fmaf(wq.z, f2, aq); ak = fmaf(wk.z, f2, ak); av = fmaf(wv.z, f2, av);
    aq = fmaf(wq.w, f3, aq); ak = fmaf(wk.w, f3, ak); av = fmaf(wv.w, f3, av);
  }
  float* qp = QKV + (b * HW + p) * O192;
  qp[o0]      = aq;
  qp[o0 + 64] = ak;
  V2[(((b << 3) + (o0 >> 3)) * HW + p) * 8 + (o0 & 7)] = av;
}

// ---------------- Kernel B: 11x11 stride-8 conv + bias + exact GELU ----------
// 1536 blocks: blk%8 = XCD slot encodes (T,b) so each XCD's L2 holds only its
// input slice (0.6 MB) + one T's weights (2 MB).  Block = (T,b,o,oy); 4 waves
// split ky; lane = c.  Input row loaded once into 48 regs, feeds all 6 ox.
__global__ __launch_bounds__(256) void conv_kernel(
    const float* __restrict__ QKV, const float* __restrict__ Wq,
    const float* __restrict__ Bq, const float* __restrict__ Wk,
    const float* __restrict__ Bk, float* __restrict__ QD) {
  __shared__ float sW[7744];        // 64 c * 121 taps for this o
  __shared__ float sRed[4 * 64 * 6];
  int blk = blockIdx.x;
  int xcd = blk & 7;
  int T = xcd >> 2, b = (xcd >> 1) & 1, s = xcd & 1;
  int idx = (blk >> 3) * 2 + s;     // 0..383
  int o  = idx / 6;
  int oy = idx % 6;
  const float* Wg = T ? Wk : Wq;
  for (int i = threadIdx.x; i < 7744; i += 256) sW[i] = Wg[o * 7744 + i];
  __syncthreads();
  int wv = threadIdx.x >> 6;
  int c  = threadIdx.x & 63;
  const float* base = QKV + b * (HW * O192) + T * 64 + c;
  float acc[6];
  #pragma unroll
  for (int ox = 0; ox < 6; ox++) acc[ox] = 0.f;
  for (int kyi = 0; kyi < 3; kyi++) {
    int ky = wv * 3 + kyi;          // waves 0..3 -> ky {0-2,3-5,6-8,9-10}
    if (ky > 10) break;             // wave-uniform
    int y = oy * 8 - 2 + ky;
    if ((unsigned)y < 48u) {        // wave-uniform
      float xrow[48];
      #pragma unroll
      for (int x = 0; x < 48; x++) xrow[x] = base[(y * 48 + x) * O192];
      #pragma unroll
      for (int kx = 0; kx < 11; kx++) {
        float wt = sW[c * 121 + ky * 11 + kx];   // 2-way alias only: free
        #pragma unroll
        for (int ox = 0; ox < 6; ox++) {
          int x = ox * 8 - 2 + kx;               // compile-time
          if (x >= 0 && x < 48) acc[ox] = fmaf(xrow[x], wt, acc[ox]);
        }
      }
    }
  }
  #pragma unroll
  for (int ox = 0; ox < 6; ox++) sRed[(wv * 64 + c) * 6 + ox] = acc[ox];
  __syncthreads();
  if (threadIdx.x < 64) {
    int t = threadIdx.x;
    float r[6];
    #pragma unroll
    for (int ox = 0; ox < 6; ox++)
      r[ox] = sRed[t * 6 + ox] + sRed[(64 + t) * 6 + ox]
            + sRed[(128 + t) * 6 + ox] + sRed[(192 + t) * 6 + ox];
    #pragma unroll
    for (int off = 32; off; off >>= 1) {
      #pragma unroll
      for (int ox = 0; ox < 6; ox++) r[ox] += __shfl_down(r[ox], off, 64);
    }
    if (t == 0) {
      float bias = T ? Bk[o] : Bq[o];
      #pragma unroll
      for (int ox = 0; ox < 6; ox++) {
        float g = r[ox] + bias;
        float ge = 0.5f * g * (1.0f + erff(g * 0.70710678118654752f));
        QD[((T * 2 + b) * 64 + o) * 36 + oy * 6 + ox] = ge;
      }
    }
  }
}

// ---------------- Kernel C: dots (36x36 per b,h) -> E = exp(scale * qd.kd) ----
__global__ __launch_bounds__(256) void dots_kernel(
    const float* __restrict__ QD, float* __restrict__ E) {
  int idx = blockIdx.x * 256 + threadIdx.x;   // 20736 = 16*36*36
  if (idx >= 16 * 36 * 36) return;
  int J  = idx % 36;
  int I  = (idx / 36) % 36;
  int bh = idx / 1296;
  int b = bh >> 3, h = bh & 7;
  float acc = 0.f;
  #pragma unroll
  for (int c8 = 0; c8 < 8; c8++) {
    float qv = QD[((0 + b) * 64 + h * 8 + c8) * 36 + I];        // T=0
    float kv = QD[((2 + b) * 64 + h * 8 + c8) * 36 + J];        // T=1
    acc = fmaf(qv, kv, acc);
  }
  E[idx] = __expf(SCALE_F * acc);
}

// ---------------- Kernel D: fused factored attention ------------------------
// One block per (b,h,I).  lane = row r (i = I*64+r); 8 waves split jy rows.
// V staged in LDS in two 1152-j phases; inner-loop V reads are ds_read
// broadcasts.  w(i,j) = E[I,J]*expA_i[jy]*expB_i[jx]; out = (sum w*v)/(sum w).
__global__ __launch_bounds__(512, 4) void attn_kernel(
    const float* __restrict__ QKV, const float* __restrict__ V2,
    const float* __restrict__ E, const float* __restrict__ PH,
    const float* __restrict__ PW, float* __restrict__ out) {
  __shared__ __align__(16) float sV[1152 * 8];   // 36864 B, one phase of V
  __shared__ __align__(16) float sPHT[48 * 8];   // PH transposed [y][c]
  __shared__ __align__(16) float sPWT[48 * 8];   // PW transposed [x][c]
  __shared__ float sE[36];
  __shared__ float sRed[8 * 64 * 9];             // 18432 B per-wave partials
  __shared__ float sZinv[64];
  int bh = blockIdx.x / 36;
  int I  = blockIdx.x % 36;
  int b = bh >> 3, h = bh & 7;
  int tid = threadIdx.x;
  if (tid < 384) sPHT[tid] = PH[(tid & 7) * 48 + (tid >> 3)];
  else { int i = tid - 384; sPWT[i] = PW[(i & 7) * 48 + (i >> 3)]; }
  if (tid < 256) { int i = tid + 128; sPWT[i] = PW[(i & 7) * 48 + (i >> 3)]; }
  if (tid < 36) sE[tid] = E[bh * 1296 + I * 36 + tid];
  int wv = tid >> 6, lane = tid & 63;
  const float* qr = QKV + (b * HW + I * 64 + lane) * O192 + h * 8;
  float4 qa = *(const float4*)qr;
  float4 qb = *(const float4*)(qr + 4);
  __syncthreads();
  float eB[48];
  #pragma unroll
  for (int x = 0; x < 48; x++) {
    float4 p0 = *(const float4*)(sPWT + x * 8);
    float4 p1 = *(const float4*)(sPWT + x * 8 + 4);
    float v = qa.x * p0.x + qa.y * p0.y + qa.z * p0.z + qa.w * p0.w
            + qb.x * p1.x + qb.y * p1.y + qb.z * p1.z + qb.w * p1.w;
    eB[x] = __expf(v);
  }
  float acc[9];
  #pragma unroll
  for (int c = 0; c < 9; c++) acc[c] = 0.f;
  const float4* vsrc = (const float4*)(V2 + (size_t)bh * (HW * 8));
  for (int p = 0; p < 2; p++) {
    __syncthreads();
    {
      float4* dst = (float4*)sV;
      #pragma unroll
      for (int k = 0; k < 5; k++) {
        int i = tid + k * 512;
        if (i < 2304) dst[i] = vsrc[p * 2304 + i];
      }
    }
    __syncthreads();
    #pragma unroll
    for (int t = 0; t < 3; t++) {
      int jy = p * 24 + wv * 3 + t;
      float4 h0 = *(const float4*)(sPHT + jy * 8);
      float4 h1 = *(const float4*)(sPHT + jy * 8 + 4);
      float eA = __expf(qa.x * h0.x + qa.y * h0.y + qa.z * h0.z + qa.w * h0.w
                      + qb.x * h1.x + qb.y * h1.y + qb.z * h1.z + qb.w * h1.w);
      #pragma unroll
      for (int c3 = 0; c3 < 6; c3++) {
        float tA = eA * sE[(jy * 6 + c3) >> 3];
        const float* vp = sV + (((jy - p * 24) * 48) + c3 * 8) * 8;
        #pragma unroll
        for (int u = 0; u < 8; u++) {
          float wgt = tA * eB[c3 * 8 + u];
          float4 lo = *(const float4*)(vp + u * 8);      // ds_read broadcast
          float4 hi = *(const float4*)(vp + u * 8 + 4);
          acc[0] = fmaf(wgt, lo.x, acc[0]);
          acc[1] = fmaf(wgt, lo.y, acc[1]);
          acc[2] = fmaf(wgt, lo.z, acc[2]);
          acc[3] = fmaf(wgt, lo.w, acc[3]);
          acc[4] = fmaf(wgt, hi.x, acc[4]);
          acc[5] = fmaf(wgt, hi.y, acc[5]);
          acc[6] = fmaf(wgt, hi.z, acc[6]);
          acc[7] = fmaf(wgt, hi.w, acc[7]);
          acc[8] += wgt;
        }
      }
    }
  }
  {
    float* rp = sRed + (wv * 64 + lane) * 9;
    #pragma unroll
    for (int c = 0; c < 9; c++) rp[c] = acc[c];
  }
  __syncthreads();
  if (tid < 64) {
    float z = 0.f;
    #pragma unroll
    for (int w = 0; w < 8; w++) z += sRed[(w * 64 + tid) * 9 + 8];
    sZinv[tid] = 1.0f / z;
  }
  __syncthreads();
  {
    int c = tid >> 6, r = tid & 63;     // c 0..7
    float v = 0.f;
    #pragma unroll
    for (int w = 0; w < 8; w++) v += sRed[(w * 64 + r) * 9 + c];
    out[(b * 64 + h * 8 + c) * HW + I * 64 + r] = v * sZinv[r];   // coalesced
  }
}

extern "C" void kernel_launch(void* const* d_in, const int* in_sizes, int n_in,
                              void* d_out, int out_size, void* d_ws, size_t ws_size,
                              hipStream_t stream) {
  const float* F    = (const float*)d_in[0];   // [2,64,48,48]
  const float* Wqkv = (const float*)d_in[1];   // [192,64,1,1]
  const float* Wq   = (const float*)d_in[2];   // [64,64,11,11]
  const float* Bq   = (const float*)d_in[3];   // [64]
  const float* Wk   = (const float*)d_in[4];   // [64,64,11,11]
  const float* Bk   = (const float*)d_in[5];   // [64]
  const float* PH   = (const float*)d_in[6];   // [8,48]
  const float* PW   = (const float*)d_in[7];   // [8,48]
  float* out = (float*)d_out;                  // [2,64,48,48] f32

  float* ws  = (float*)d_ws;
  float* QKV = ws;                      // 2*2304*192   = 884736 floats
  float* V2  = QKV + 2 * HW * O192;     // 2*8*2304*8   = 294912 floats
  float* QD  = V2 + 2 * 8 * HW * 8;     // 2*2*64*36    = 9216 floats
  float* E   = QD + 2 * 2 * 64 * 36;    // 16*36*36     = 20736 floats

  qkv_kernel <<<1152, 256, 0, stream>>>(F, Wqkv, QKV, V2);
  conv_kernel<<<1536, 256, 0, stream>>>(QKV, Wq, Bq, Wk, Bk, QD);
  dots_kernel<<<81,   256, 0, stream>>>(QD, E);
  attn_kernel<<<576,  512, 0, stream>>>(QKV, V2, E, PH, PW, out);
}

// Round 4
// 141.757 us; speedup vs baseline: 1.9700x; 1.0114x over previous
//
#include <hip/hip_runtime.h>
#include <math.h>

#define HW 2304           // 48*48
#define O192 192
#define SCALE_F 0.35355339059327373f   // 8^-0.5

typedef unsigned int u32;
typedef __attribute__((address_space(1))) const u32 gu32;
typedef __attribute__((address_space(3))) u32 lu32;
// async global->LDS DMA, 16B per lane; LDS dest = wave-uniform base + lane*16
__device__ __forceinline__ void dma16(const void* g, void* l) {
  __builtin_amdgcn_global_load_lds((gu32*)g, (lu32*)l, 16, 0, 0);
}

// ---------------- Kernel A: 1x1 conv -> q,k (QKV) and v (V2) ----------------
__global__ __launch_bounds__(256) void qkv_kernel(
    const float* __restrict__ F, const float* __restrict__ W,
    float* __restrict__ QKV, float* __restrict__ V2) {
  __shared__ __align__(16) float sW[384];   // two o0 sets x {q,k,v} rows x 64
  int blk = blockIdx.x;
  int idx0 = blk * 256;
  int r0 = idx0 / HW;
  int r1 = (idx0 + 255) / HW;
  int tid = threadIdx.x;
  if (tid < 192) {
    int g = tid >> 6, c = tid & 63;
    sW[tid]       = W[((r0 & 63) + g * 64) * 64 + c];
    sW[192 + tid] = W[((r1 & 63) + g * 64) * 64 + c];
  }
  __syncthreads();
  int idx = idx0 + tid;
  int p  = idx % HW;
  int r  = idx / HW;
  int o0 = r & 63;
  int b  = r >> 6;
  const float4* w4 = (const float4*)(sW + ((r == r0) ? 0 : 192));
  const float* f = F + (b * 64) * HW + p;
  float aq = 0.f, ak = 0.f, av = 0.f;
  #pragma unroll 4
  for (int c4 = 0; c4 < 16; c4++) {
    float4 wq = w4[c4];
    float4 wk = w4[16 + c4];
    float4 wv = w4[32 + c4];
    float f0 = f[(c4 * 4 + 0) * HW];
    float f1 = f[(c4 * 4 + 1) * HW];
    float f2 = f[(c4 * 4 + 2) * HW];
    float f3 = f[(c4 * 4 + 3) * HW];
    aq = fmaf(wq.x, f0, aq); ak = fmaf(wk.x, f0, ak); av = fmaf(wv.x, f0, av);
    aq = fmaf(wq.y, f1, aq); ak = fmaf(wk.y, f1, ak); av = fmaf(wv.y, f1, av);
    aq = fmaf(wq.z, f2, aq); ak = fmaf(wk.z, f2, ak); av = fmaf(wv.z, f2, av);
    aq = fmaf(wq.w, f3, aq); ak = fmaf(wk.w, f3, ak); av = fmaf(wv.w, f3, av);
  }
  float* qp = QKV + (b * HW + p) * O192;
  qp[o0]      = aq;
  qp[o0 + 64] = ak;
  V2[(((b << 3) + (o0 >> 3)) * HW + p) * 8 + (o0 & 7)] = av;
}

// ---------------- Kernel B: 11x11 stride-8 conv + bias + exact GELU ----------
__global__ __launch_bounds__(256) void conv_kernel(
    const float* __restrict__ QKV, const float* __restrict__ Wq,
    const float* __restrict__ Bq, const float* __restrict__ Wk,
    const float* __restrict__ Bk, float* __restrict__ QD) {
  __shared__ float sW[7744];
  __shared__ float sRed[4 * 64 * 6];
  int blk = blockIdx.x;
  int xcd = blk & 7;
  int T = xcd >> 2, b = (xcd >> 1) & 1, s = xcd & 1;
  int idx = (blk >> 3) * 2 + s;
  int o  = idx / 6;
  int oy = idx % 6;
  const float* Wg = T ? Wk : Wq;
  for (int i = threadIdx.x; i < 7744; i += 256) sW[i] = Wg[o * 7744 + i];
  __syncthreads();
  int wv = threadIdx.x >> 6;
  int c  = threadIdx.x & 63;
  const float* base = QKV + b * (HW * O192) + T * 64 + c;
  float acc[6];
  #pragma unroll
  for (int ox = 0; ox < 6; ox++) acc[ox] = 0.f;
  for (int kyi = 0; kyi < 3; kyi++) {
    int ky = wv * 3 + kyi;
    if (ky > 10) break;
    int y = oy * 8 - 2 + ky;
    if ((unsigned)y < 48u) {
      float xrow[48];
      #pragma unroll
      for (int x = 0; x < 48; x++) xrow[x] = base[(y * 48 + x) * O192];
      #pragma unroll
      for (int kx = 0; kx < 11; kx++) {
        float wt = sW[c * 121 + ky * 11 + kx];
        #pragma unroll
        for (int ox = 0; ox < 6; ox++) {
          int x = ox * 8 - 2 + kx;
          if (x >= 0 && x < 48) acc[ox] = fmaf(xrow[x], wt, acc[ox]);
        }
      }
    }
  }
  #pragma unroll
  for (int ox = 0; ox < 6; ox++) sRed[(wv * 64 + c) * 6 + ox] = acc[ox];
  __syncthreads();
  if (threadIdx.x < 64) {
    int t = threadIdx.x;
    float r[6];
    #pragma unroll
    for (int ox = 0; ox < 6; ox++)
      r[ox] = sRed[t * 6 + ox] + sRed[(64 + t) * 6 + ox]
            + sRed[(128 + t) * 6 + ox] + sRed[(192 + t) * 6 + ox];
    #pragma unroll
    for (int off = 32; off; off >>= 1) {
      #pragma unroll
      for (int ox = 0; ox < 6; ox++) r[ox] += __shfl_down(r[ox], off, 64);
    }
    if (t == 0) {
      float bias = T ? Bk[o] : Bq[o];
      #pragma unroll
      for (int ox = 0; ox < 6; ox++) {
        float g = r[ox] + bias;
        float ge = 0.5f * g * (1.0f + erff(g * 0.70710678118654752f));
        QD[((T * 2 + b) * 64 + o) * 36 + oy * 6 + ox] = ge;
      }
    }
  }
}

// ---------------- Kernel C: dots -> E = exp(scale * qd.kd) -------------------
__global__ __launch_bounds__(256) void dots_kernel(
    const float* __restrict__ QD, float* __restrict__ E) {
  int idx = blockIdx.x * 256 + threadIdx.x;
  if (idx >= 16 * 36 * 36) return;
  int J  = idx % 36;
  int I  = (idx / 36) % 36;
  int bh = idx / 1296;
  int b = bh >> 3, h = bh & 7;
  float acc = 0.f;
  #pragma unroll
  for (int c8 = 0; c8 < 8; c8++) {
    float qv = QD[((0 + b) * 64 + h * 8 + c8) * 36 + I];
    float kv = QD[((2 + b) * 64 + h * 8 + c8) * 36 + J];
    acc = fmaf(qv, kv, acc);
  }
  E[idx] = __expf(SCALE_F * acc);
}

// ---------------- Kernel D: factored attention, 4 rows/lane, jx-split -------
// 576 blocks = (bh:16, S:9 row-supertile of 256, q:4 jy-quarter of 12).
// 8 waves; wave w owns jx in [6w,6w+6); lane holds rows {k*64+lane, k<4}.
// Each broadcast V read now feeds 256 rows (4 rows/lane) -> 4x fewer ds_reads.
// Partial num/Z written to workspace; combine_kernel sums quarters+normalizes.
#define OFF_V   0        // 4608 f  : V quarter [12jy][48jx][8c]
#define OFF_EA  4608     // 3072 f  : eA [jyL][lane][k]
#define OFF_PHT 7680     // 384  f  : PH^T [jy][c]
#define OFF_PWT 8064     // 384  f  : PW^T [jx][c]
#define OFF_E4  8448     // 144  f  : E [J][k]
#define OFF_U   8592     // 4608 f  : union: sQ (2048) then sRed (4608)
#define SBUF_N  13200    // 52.8 KB

__global__ __launch_bounds__(512, 4) void attn_kernel(
    const float* __restrict__ QKV, const float* __restrict__ V2,
    const float* __restrict__ E, const float* __restrict__ PH,
    const float* __restrict__ PW, float* __restrict__ Pnum,
    float* __restrict__ PZ) {
  __shared__ __align__(16) float sB[SBUF_N];
  int blk = blockIdx.x;
  int bh = blk / 36;
  int rem = blk - bh * 36;
  int q = rem & 3, S = rem >> 2;
  int b = bh >> 3, h = bh & 7;
  int tid = threadIdx.x;
  int w = tid >> 6, lane = tid & 63;
  // ---- stage tables ----
  if (tid < 384) {
    sB[OFF_PHT + tid] = PH[(tid & 7) * 48 + (tid >> 3)];
    sB[OFF_PWT + tid] = PW[(tid & 7) * 48 + (tid >> 3)];
  }
  if (tid < 144) {
    int J = tid >> 2, k = tid & 3;
    sB[OFF_E4 + tid] = E[bh * 1296 + (S * 4 + k) * 36 + J];
  }
  { // q rows of this supertile: sQ[row][8]
    int row = tid >> 1, half = tid & 1;
    *(float4*)(sB + OFF_U + tid * 4) =
      *(const float4*)(QKV + (b * HW + S * 256 + row) * O192 + h * 8 + half * 4);
  }
  { // V quarter via DMA: 18 chunks x 1 KiB, contiguous
    const char* src = (const char*)(V2 + (size_t)bh * (HW * 8) + q * 4608);
    for (int m = w; m < 18; m += 8)
      dma16(src + m * 1024 + lane * 16, (char*)(sB + OFF_V) + m * 1024);
  }
  __syncthreads();
  // ---- eA table: exp(q_row . PH[:,jy]) ----
  #pragma unroll
  for (int m = 0; m < 6; m++) {
    int flat = tid + m * 512;           // jyL*256 + lane*4 + k
    int jyL = flat >> 8, rl = flat & 255;
    int ln = rl >> 2, kk = rl & 3;
    const float* qp = sB + OFF_U + (kk * 64 + ln) * 8;
    const float* pp = sB + OFF_PHT + (q * 12 + jyL) * 8;
    float d = qp[0]*pp[0]+qp[1]*pp[1]+qp[2]*pp[2]+qp[3]*pp[3]
            + qp[4]*pp[4]+qp[5]*pp[5]+qp[6]*pp[6]+qp[7]*pp[7];
    sB[OFF_EA + flat] = __expf(d);
  }
  // ---- eB regs for this wave's 6 jx x 4 rows ----
  float eB[4][6];
  #pragma unroll
  for (int k = 0; k < 4; k++) {
    const float* qp = sB + OFF_U + (k * 64 + lane) * 8;
    #pragma unroll
    for (int i = 0; i < 6; i++) {
      const float* pp = sB + OFF_PWT + (w * 6 + i) * 8;
      float d = qp[0]*pp[0]+qp[1]*pp[1]+qp[2]*pp[2]+qp[3]*pp[3]
              + qp[4]*pp[4]+qp[5]*pp[5]+qp[6]*pp[6]+qp[7]*pp[7];
      eB[k][i] = __expf(d);
    }
  }
  __syncthreads();
  // ---- main loop over this quarter's 12 jy ----
  float acc[4][9];
  #pragma unroll
  for (int k = 0; k < 4; k++)
    #pragma unroll
    for (int c = 0; c < 9; c++) acc[k][c] = 0.f;
  const float4* sV4 = (const float4*)(sB + OFF_V);
  for (int jyL = 0; jyL < 12; jyL++) {
    float4 eAk = *(const float4*)(sB + OFF_EA + jyL * 256 + lane * 4);
    int cb = (q * 12 + jyL) * 48 + w * 6;     // global j of i=0
    int J0 = cb >> 6, J1 = (cb + 5) >> 6;
    int ib = 64 - (cb & 63);                  // i >= ib uses J1
    float4 e0 = *(const float4*)(sB + OFF_E4 + J0 * 4);
    float4 e1 = *(const float4*)(sB + OFF_E4 + J1 * 4);
    float a0[4] = {eAk.x*e0.x, eAk.y*e0.y, eAk.z*e0.z, eAk.w*e0.w};
    float a1[4] = {eAk.x*e1.x, eAk.y*e1.y, eAk.z*e1.z, eAk.w*e1.w};
    #pragma unroll
    for (int i = 0; i < 6; i++) {
      float4 vlo = sV4[(jyL * 48 + w * 6 + i) * 2];
      float4 vhi = sV4[(jyL * 48 + w * 6 + i) * 2 + 1];
      bool sel = (i < ib);
      #pragma unroll
      for (int k = 0; k < 4; k++) {
        float wgt = (sel ? a0[k] : a1[k]) * eB[k][i];
        acc[k][0] = fmaf(wgt, vlo.x, acc[k][0]);
        acc[k][1] = fmaf(wgt, vlo.y, acc[k][1]);
        acc[k][2] = fmaf(wgt, vlo.z, acc[k][2]);
        acc[k][3] = fmaf(wgt, vlo.w, acc[k][3]);
        acc[k][4] = fmaf(wgt, vhi.x, acc[k][4]);
        acc[k][5] = fmaf(wgt, vhi.y, acc[k][5]);
        acc[k][6] = fmaf(wgt, vhi.z, acc[k][6]);
        acc[k][7] = fmaf(wgt, vhi.w, acc[k][7]);
        acc[k][8] += wgt;
      }
    }
  }
  // ---- cross-wave reduction, one k-group (64 rows) per round ----
  float* sU = sB + OFF_U;   // sQ dead
  #pragma unroll
  for (int k = 0; k < 4; k++) {
    #pragma unroll
    for (int c = 0; c < 9; c++) sU[(w * 64 + lane) * 9 + c] = acc[k][c];
    __syncthreads();
    {
      int c = tid >> 6, r = tid & 63;
      float num = 0.f;
      #pragma unroll
      for (int ww = 0; ww < 8; ww++) num += sU[(ww * 64 + r) * 9 + c];
      Pnum[((q * 16 + bh) * 8 + c) * HW + S * 256 + k * 64 + r] = num;
      if (tid < 64) {
        float z = 0.f;
        #pragma unroll
        for (int ww = 0; ww < 8; ww++) z += sU[(ww * 64 + tid) * 9 + 8];
        PZ[(q * 16 + bh) * HW + S * 256 + k * 64 + tid] = z;
      }
    }
    __syncthreads();
  }
}

// ---------------- Kernel E: combine 4 jy-quarters + normalize ---------------
__global__ __launch_bounds__(256) void combine_kernel(
    const float* __restrict__ Pnum, const float* __restrict__ PZ,
    float* __restrict__ out) {
  int t = blockIdx.x * 256 + threadIdx.x;   // 294912
  int row = t % HW;
  int rc = t / HW;        // bh*8 + c
  int c = rc & 7, bh = rc >> 3;
  float num = 0.f, z = 0.f;
  #pragma unroll
  for (int q = 0; q < 4; q++) {
    num += Pnum[((q * 16 + bh) * 8 + c) * HW + row];
    z   += PZ[(q * 16 + bh) * HW + row];
  }
  int b = bh >> 3, h = bh & 7;
  out[(b * 64 + h * 8 + c) * HW + row] = num / z;
}

extern "C" void kernel_launch(void* const* d_in, const int* in_sizes, int n_in,
                              void* d_out, int out_size, void* d_ws, size_t ws_size,
                              hipStream_t stream) {
  const float* F    = (const float*)d_in[0];
  const float* Wqkv = (const float*)d_in[1];
  const float* Wq   = (const float*)d_in[2];
  const float* Bq   = (const float*)d_in[3];
  const float* Wk   = (const float*)d_in[4];
  const float* Bk   = (const float*)d_in[5];
  const float* PH   = (const float*)d_in[6];
  const float* PW   = (const float*)d_in[7];
  float* out = (float*)d_out;

  float* ws   = (float*)d_ws;
  float* QKV  = ws;                        // 884736
  float* V2   = QKV + 2 * HW * O192;       // 294912
  float* QD   = V2 + 2 * 8 * HW * 8;       // 9216
  float* E    = QD + 2 * 2 * 64 * 36;      // 20736
  float* Pnum = E + 16 * 36 * 36;          // 4*16*8*2304 = 1179648
  float* PZ   = Pnum + 4 * 16 * 8 * HW;    // 4*16*2304   = 147456
                                           // total ~9.7 MB

  qkv_kernel    <<<1152, 256, 0, stream>>>(F, Wqkv, QKV, V2);
  conv_kernel   <<<1536, 256, 0, stream>>>(QKV, Wq, Bq, Wk, Bk, QD);
  dots_kernel   <<<81,   256, 0, stream>>>(QD, E);
  attn_kernel   <<<576,  512, 0, stream>>>(QKV, V2, E, PH, PW, Pnum, PZ);
  combine_kernel<<<1152, 256, 0, stream>>>(Pnum, PZ, out);
}